// Round 1
// baseline (1409.446 us; speedup 1.0000x reference)
//
#include <hip/hip_runtime.h>
#include <hip/hip_bf16.h>
#include <stdint.h>

// Problem constants
#define SEQ   2048
#define NHEAD 32
#define HDIM  128
#define DMODEL 4096
#define MTOT  4096          // B*S
#define RSCALE 0.08838834764831845f  // 1/sqrt(128)

typedef __hip_bfloat16 bf16_t;
typedef __attribute__((ext_vector_type(8))) short short8v;
typedef __attribute__((ext_vector_type(4))) float f32x4;

typedef __attribute__((address_space(3))) void lds_void;
typedef __attribute__((address_space(1))) void gbl_void;
#define TO_LDS(p) ((lds_void*)(uint32_t)(uintptr_t)(p))
#define TO_GBL(p) ((gbl_void*)(uintptr_t)(p))
#define ASYNC_CP16(g, l) __builtin_amdgcn_global_load_lds(TO_GBL(g), TO_LDS(l), 16, 0, 0)

__device__ __forceinline__ float bf2f(short u) {
  union { uint32_t i; float f; } x; x.i = ((uint32_t)(uint16_t)u) << 16; return x.f;
}

// ---------------------------------------------------------------- cast f32->bf16
__global__ __launch_bounds__(256) void cast_f32_to_bf16(const float* __restrict__ in,
                                                        bf16_t* __restrict__ out) {
  size_t i = (size_t)blockIdx.x * 256 + threadIdx.x;   // 8 elems per thread
  const f32x4* p = (const f32x4*)in + i * 2;
  f32x4 a = p[0], b = p[1];
  __align__(16) bf16_t tmp[8];
#pragma unroll
  for (int j = 0; j < 4; ++j) tmp[j]     = __float2bfloat16(a[j]);
#pragma unroll
  for (int j = 0; j < 4; ++j) tmp[4 + j] = __float2bfloat16(b[j]);
  *(short8v*)(out + i * 8) = *(const short8v*)tmp;
}

// ---------------------------------------------------------------- NT GEMM: C = A @ B^T
// A: MTOT x 4096 bf16 row-major, B: 4096 x 4096 bf16 row-major (W, so C = A@W^T)
// 128x128 tile, BK=32, 4 waves, 16x16x32 MFMA (m97 structure)
template <bool OUT_BF16>
__global__ __launch_bounds__(256) void gemm_nt(const bf16_t* __restrict__ A,
                                               const bf16_t* __restrict__ B0,
                                               const bf16_t* __restrict__ B1,
                                               const bf16_t* __restrict__ B2,
                                               void* __restrict__ Cout) {
  __shared__ bf16_t Als[128 * 32];
  __shared__ bf16_t Bls[128 * 32];
  const int z = blockIdx.z;
  const bf16_t* __restrict__ Bm = (z == 0) ? B0 : (z == 1 ? B1 : B2);
  const int tid = threadIdx.x;
  const int bm = blockIdx.y, bn = blockIdx.x;
  const int wave = tid >> 6, lane = tid & 63;
  const int wr = wave >> 1, wc = wave & 1;
  const int r = lane & 15, g = lane >> 4;

  f32x4 acc[4][4] = {};

  // staging address precompute: 8KB tile = 2 x (256 thr x 16B)
  const int off0 = tid * 16;               // byte offset in tile
  const int row0 = off0 >> 6;              // 64B per row (BK=32 bf16)
  const int col0 = (off0 & 63) >> 1;       // element col
  const int off1 = 4096 + tid * 16;
  const int row1 = off1 >> 6;
  const int col1 = (off1 & 63) >> 1;
  const bf16_t* ga0 = A  + ((size_t)bm * 128 + row0) * 4096 + col0;
  const bf16_t* ga1 = A  + ((size_t)bm * 128 + row1) * 4096 + col1;
  const bf16_t* gb0 = Bm + ((size_t)bn * 128 + row0) * 4096 + col0;
  const bf16_t* gb1 = Bm + ((size_t)bn * 128 + row1) * 4096 + col1;

  for (int k0 = 0; k0 < 4096; k0 += 32) {
    ASYNC_CP16(ga0 + k0, (char*)Als + off0);
    ASYNC_CP16(ga1 + k0, (char*)Als + off1);
    ASYNC_CP16(gb0 + k0, (char*)Bls + off0);
    ASYNC_CP16(gb1 + k0, (char*)Bls + off1);
    __syncthreads();

    short8v a[4], b[4];
#pragma unroll
    for (int m = 0; m < 4; ++m)
      a[m] = *(const short8v*)((const char*)Als + (wr * 64 + m * 16 + r) * 64 + g * 16);
#pragma unroll
    for (int n = 0; n < 4; ++n)
      b[n] = *(const short8v*)((const char*)Bls + (wc * 64 + n * 16 + r) * 64 + g * 16);
#pragma unroll
    for (int m = 0; m < 4; ++m)
#pragma unroll
      for (int n = 0; n < 4; ++n)
        acc[m][n] = __builtin_amdgcn_mfma_f32_16x16x32_bf16(a[m], b[n], acc[m][n], 0, 0, 0);
    __syncthreads();
  }

  const size_t row_base = (size_t)bm * 128 + wr * 64 + g * 4;
  const size_t col_base = (size_t)bn * 128 + wc * 64 + r;
  if (OUT_BF16) {
    bf16_t* C = (bf16_t*)Cout + (size_t)z * 16777216u;
#pragma unroll
    for (int m = 0; m < 4; ++m)
#pragma unroll
      for (int n = 0; n < 4; ++n)
#pragma unroll
        for (int j = 0; j < 4; ++j)
          C[(row_base + m * 16 + j) * 4096 + col_base + n * 16] = __float2bfloat16(acc[m][n][j]);
  } else {
    float* C = (float*)Cout;
#pragma unroll
    for (int m = 0; m < 4; ++m)
#pragma unroll
      for (int n = 0; n < 4; ++n)
#pragma unroll
        for (int j = 0; j < 4; ++j)
          C[(row_base + m * 16 + j) * 4096 + col_base + n * 16] = acc[m][n][j];
  }
}

// ---------------------------------------------------------------- RoPE + relayout
// in : qkv[which]  [(b*S+s)*4096 + h*128 + d]   (bf16)
// out: rot         [((b*NH+h)*S+s)*128 + d]     (bf16)
__global__ __launch_bounds__(256) void rope_kernel(const bf16_t* __restrict__ qkv,
                                                   const float* __restrict__ freqs,
                                                   bf16_t* __restrict__ qrot,
                                                   bf16_t* __restrict__ krot) {
  const int which = blockIdx.y;
  const bf16_t* __restrict__ src = qkv + (size_t)which * 16777216u;
  bf16_t* __restrict__ dst = (which == 0) ? qrot : krot;
  size_t t = (size_t)blockIdx.x * 256 + threadIdx.x;   // [bh:6][s:11][dg:4]
  int dg = t & 15;
  int s  = (int)(t >> 4) & 2047;
  int bh = (int)(t >> 15);
  int b  = bh >> 5;
  int d0 = dg * 8;

  short8v v = *(const short8v*)&src[((size_t)(b * 2048 + s)) * 4096 + (bh & 31) * 128 + d0];
  const float* fp = freqs + (size_t)s * 128 + d0;   // [s][d2][2] -> 8 consecutive floats
  f32x4 f0 = *(const f32x4*)fp;
  f32x4 f1 = *(const f32x4*)(fp + 4);
  float fr[4] = {f0[0], f0[2], f1[0], f1[2]};
  float fi[4] = {f0[1], f0[3], f1[1], f1[3]};
  __align__(16) bf16_t tmp[8];
#pragma unroll
  for (int i = 0; i < 4; ++i) {
    float tr = bf2f(v[2 * i]), ti = bf2f(v[2 * i + 1]);
    tmp[2 * i]     = __float2bfloat16(tr * fr[i] - ti * fi[i]);
    tmp[2 * i + 1] = __float2bfloat16(tr * fi[i] + ti * fr[i]);
  }
  *(short8v*)&dst[((size_t)bh * 2048 + s) * 128 + d0] = *(const short8v*)tmp;
}

// ---------------------------------------------------------------- V transpose
// in : xv [(b*S+s)*4096 + h*128 + d]      out: vt [((b*NH+h)*128 + d)*2048 + s]
__global__ __launch_bounds__(256) void vtrans_kernel(const bf16_t* __restrict__ xv,
                                                     bf16_t* __restrict__ vt) {
  __shared__ bf16_t tile[64 * 136];     // 64 s-rows x 128 d (pad to 136)
  const int s0 = blockIdx.x * 64;
  const int bh = blockIdx.y;
  const int b = bh >> 5, h = bh & 31;
  const int tid = threadIdx.x;
#pragma unroll
  for (int it = 0; it < 4; ++it) {
    int c = it * 256 + tid;             // 1024 chunks of 8 elems
    int row = c >> 4, col8 = c & 15;
    short8v v = *(const short8v*)&xv[((size_t)(b * 2048 + s0 + row)) * 4096 + h * 128 + col8 * 8];
    *(short8v*)&tile[row * 136 + col8 * 8] = v;
  }
  __syncthreads();
#pragma unroll
  for (int it = 0; it < 4; ++it) {
    int c = it * 256 + tid;             // d = c>>3 (128), sc = c&7
    int d = c >> 3, sc = c & 7;
    __align__(16) bf16_t tmp[8];
#pragma unroll
    for (int i = 0; i < 8; ++i) tmp[i] = tile[(sc * 8 + i) * 136 + d];
    *(short8v*)&vt[((size_t)(bh * 128 + d)) * 2048 + s0 + sc * 8] = *(const short8v*)tmp;
  }
}

// ---------------------------------------------------------------- flash attention
// qrot/krot: [((b*NH+h)*S+s)*128+d], vt: [((b*NH+h)*128+d)*S+s]
// out att:   [(b*S+s)*4096 + h*128 + d]  (bf16)
__global__ __launch_bounds__(64) void attn_kernel(const bf16_t* __restrict__ qrot,
                                                  const bf16_t* __restrict__ krot,
                                                  const bf16_t* __restrict__ vt,
                                                  bf16_t* __restrict__ att) {
  const int qt = blockIdx.x;            // 0..127  (16 q-rows each)
  const int bh = blockIdx.y;            // 0..63
  const int lane = threadIdx.x;
  const int r = lane & 15, g = lane >> 4;
  const bf16_t* __restrict__ Q  = qrot + (size_t)bh * 2048 * 128;
  const bf16_t* __restrict__ Kp = krot + (size_t)bh * 2048 * 128;
  const bf16_t* __restrict__ Vt = vt   + (size_t)bh * 128 * 2048;
  const int qb = qt * 16;

  short8v qf[4];
#pragma unroll
  for (int kk = 0; kk < 4; ++kk)
    qf[kk] = *(const short8v*)&Q[(size_t)(qb + r) * 128 + kk * 32 + g * 8];

  float mrow[4], lrow[4];
  f32x4 o[8];
#pragma unroll
  for (int j = 0; j < 4; ++j) { mrow[j] = -INFINITY; lrow[j] = 0.f; }
#pragma unroll
  for (int n2 = 0; n2 < 8; ++n2) o[n2] = f32x4{0.f, 0.f, 0.f, 0.f};

  __shared__ bf16_t Pl[16 * 72];        // P tile, padded stride 72

  const int ntiles = ((qb + 15) >> 6) + 1;
  for (int t = 0; t < ntiles; ++t) {
    const int kb = t * 64;
    f32x4 sacc[4];
#pragma unroll
    for (int n = 0; n < 4; ++n) sacc[n] = f32x4{0.f, 0.f, 0.f, 0.f};
#pragma unroll
    for (int n = 0; n < 4; ++n)
#pragma unroll
      for (int kk = 0; kk < 4; ++kk) {
        short8v kf = *(const short8v*)&Kp[(size_t)(kb + n * 16 + r) * 128 + kk * 32 + g * 8];
        sacc[n] = __builtin_amdgcn_mfma_f32_16x16x32_bf16(qf[kk], kf, sacc[n], 0, 0, 0);
      }

    const bool needmask = (t == ntiles - 1);
    float p[4][4];
#pragma unroll
    for (int j = 0; j < 4; ++j) {
      const int qg = qb + g * 4 + j;
      float mx = -INFINITY;
#pragma unroll
      for (int n = 0; n < 4; ++n) {
        float v = sacc[n][j] * RSCALE;
        if (needmask && (kb + n * 16 + r) > qg) v = -1e9f;
        p[n][j] = v;
        mx = fmaxf(mx, v);
      }
      for (int d = 1; d < 16; d <<= 1) mx = fmaxf(mx, __shfl_xor(mx, d, 64));
      const float mnew = fmaxf(mrow[j], mx);
      const float sc = __expf(mrow[j] - mnew);
      mrow[j] = mnew;
      float rs = 0.f;
#pragma unroll
      for (int n = 0; n < 4; ++n) { float e = __expf(p[n][j] - mnew); p[n][j] = e; rs += e; }
      for (int d = 1; d < 16; d <<= 1) rs += __shfl_xor(rs, d, 64);
      lrow[j] = lrow[j] * sc + rs;
#pragma unroll
      for (int n2 = 0; n2 < 8; ++n2) o[n2][j] *= sc;
    }

    // stage P into LDS in A-operand layout source (row-major 16x64, stride 72)
#pragma unroll
    for (int j = 0; j < 4; ++j)
#pragma unroll
      for (int n = 0; n < 4; ++n)
        Pl[(g * 4 + j) * 72 + n * 16 + r] = __float2bfloat16(p[n][j]);
    __syncthreads();

#pragma unroll
    for (int kk2 = 0; kk2 < 2; ++kk2) {
      short8v pf = *(const short8v*)&Pl[r * 72 + kk2 * 32 + g * 8];
#pragma unroll
      for (int n2 = 0; n2 < 8; ++n2) {
        short8v vf = *(const short8v*)&Vt[(size_t)(n2 * 16 + r) * 2048 + kb + kk2 * 32 + g * 8];
        o[n2] = __builtin_amdgcn_mfma_f32_16x16x32_bf16(pf, vf, o[n2], 0, 0, 0);
      }
    }
    __syncthreads();
  }

  float inv[4];
#pragma unroll
  for (int j = 0; j < 4; ++j) inv[j] = 1.0f / lrow[j];
  const int b = bh >> 5, h = bh & 31;
#pragma unroll
  for (int n2 = 0; n2 < 8; ++n2)
#pragma unroll
    for (int j = 0; j < 4; ++j)
      att[((size_t)(b * 2048 + qb + g * 4 + j)) * 4096 + h * 128 + n2 * 16 + r] =
          __float2bfloat16(o[n2][j] * inv[j]);
}

// ---------------------------------------------------------------- launch
extern "C" void kernel_launch(void* const* d_in, const int* in_sizes, int n_in,
                              void* d_out, int out_size, void* d_ws, size_t ws_size,
                              hipStream_t stream) {
  (void)in_sizes; (void)n_in; (void)out_size; (void)ws_size;
  const float* x  = (const float*)d_in[0];
  const float* fr = (const float*)d_in[1];
  const float* wq = (const float*)d_in[3];
  const float* wk = (const float*)d_in[4];
  const float* wv = (const float*)d_in[5];
  const float* wo = (const float*)d_in[6];

  char* ws = (char*)d_ws;
  const size_t MB32 = 33554432;
  bf16_t* xb  = (bf16_t*)(ws + 0 * MB32);   // later: q_rot
  bf16_t* wqb = (bf16_t*)(ws + 1 * MB32);   // later: k_rot
  bf16_t* wkb = (bf16_t*)(ws + 2 * MB32);   // later: v_t
  bf16_t* wvb = (bf16_t*)(ws + 3 * MB32);   // later: att_out
  bf16_t* qkv = (bf16_t*)(ws + 4 * MB32);   // 96MB (q,k,v) ; q slot reused for wo_b

  // casts
  cast_f32_to_bf16<<<8192, 256, 0, stream>>>(x,  xb);
  cast_f32_to_bf16<<<8192, 256, 0, stream>>>(wq, wqb);
  cast_f32_to_bf16<<<8192, 256, 0, stream>>>(wk, wkb);
  cast_f32_to_bf16<<<8192, 256, 0, stream>>>(wv, wvb);

  // qkv projections (z = 0,1,2)
  gemm_nt<true><<<dim3(32, 32, 3), 256, 0, stream>>>(xb, wqb, wkb, wvb, (void*)qkv);

  bf16_t* qrot = xb;
  bf16_t* krot = wqb;
  bf16_t* vtp  = wkb;
  bf16_t* attb = wvb;

  rope_kernel<<<dim3(8192, 2), 256, 0, stream>>>(qkv, fr, qrot, krot);
  vtrans_kernel<<<dim3(32, 64), 256, 0, stream>>>(qkv + 2 * 16777216u, vtp);

  // wo cast into the (now dead) q slot of qkv
  bf16_t* wob = qkv;
  cast_f32_to_bf16<<<8192, 256, 0, stream>>>(wo, wob);

  attn_kernel<<<dim3(128, 64), 64, 0, stream>>>(qrot, krot, vtp, attb);

  // final projection, fp32 out
  gemm_nt<false><<<dim3(32, 32, 1), 256, 0, stream>>>(attb, wob, wob, wob, d_out);
}